// Round 7
// baseline (168.963 us; speedup 1.0000x reference)
//
#include <hip/hip_runtime.h>
#include <cstdint>

// ---------------- problem constants ----------------
#define DD     256
#define HH     1024
#define NNSEQ  4096
#define MT     32            // tokens per block (grid 512 = 2 blocks/CU)
#define XR     46            // MT + 14 halo rows
#define XPITCH 264           // 256 + 8 pad (bf16 elems), row 528 B
#define SLOTP  260           // fp32 slot pitch
#define EPSLN  1e-5f

typedef unsigned short u16;
typedef __attribute__((ext_vector_type(8))) short short8;
typedef __attribute__((ext_vector_type(4))) float f32x4;

#define MFMA(a, b, c) __builtin_amdgcn_mfma_f32_16x16x32_bf16(a, b, c, 0, 0, 0)

__device__ __forceinline__ u16 f2bf(float f) {           // RNE fp32 -> bf16
  unsigned u = __float_as_uint(f);
  u += 0x7FFF + ((u >> 16) & 1);
  return (u16)(u >> 16);
}
__device__ __forceinline__ float bf2f(u16 s) { return __uint_as_float(((unsigned)s) << 16); }

// tanh-form GELU via sigmoid identity: 0.5v(1+tanh(u)) = v*sigmoid(2u).
// Max |err| vs exact erf-GELU ~3e-4, under the bf16 quantization applied after.
__device__ __forceinline__ float fast_gelu(float v) {
  const float e = __expf(v * __builtin_fmaf(v * v, -0.0713548163f, -1.5957691216f));
  return v * __builtin_amdgcn_rcpf(1.f + e);
}

// ======== prep: pack weights into MFMA B-fragment slabs (unchanged) ========
// slab: 32 K-rows x 256 N-cols fp32 -> 8192 bf16:
//   dst[fi*512 + l*8 + j] = W[k = s*32 + (l>>4)*8 + j][n = fi*16 + (l&15)]
__global__ __launch_bounds__(256) void k_prep(
    const float* __restrict__ wmix, const float* __restrict__ wff1,
    const float* __restrict__ wff2, u16* __restrict__ wpk,
    u16* __restrict__ w1pk, u16* __restrict__ w2pk)
{
  __shared__ float t[32][257];
  const int b = blockIdx.x, tid = threadIdx.x;

  u16* dst;
  if (b < 120) {                                   // conv: slab s = b
    dst = wpk + (size_t)b * 8192;
    for (int r = 0; r < 32; ++r)
      t[r][tid] = wmix[(size_t)(b * 32 + r) * 256 + tid];
  } else if (b < 152) {                            // FF1: u = c2*8+s
    const int u = b - 120, c2 = u >> 3, s = u & 7;
    dst = w1pk + (size_t)u * 8192;
    for (int r = 0; r < 32; ++r)
      t[r][tid] = wff1[(size_t)(s * 32 + r) * 1024 + c2 * 256 + tid];
  } else {                                         // FF2: u = c2*8+s
    const int u = b - 152, c2 = u >> 3, s = u & 7;
    dst = w2pk + (size_t)u * 8192;
    for (int r = 0; r < 32; ++r)
      t[r][tid] = wff2[(size_t)(c2 * 256 + s * 32 + r) * 256 + tid];
  }
  __syncthreads();

  const int l = tid & 63, q = l >> 4, cl = l & 15;
#pragma unroll
  for (int f = 0; f < 4; ++f) {
    const int fi = f * 4 + (tid >> 6);
    const int n = fi * 16 + cl;
    uint4 pk;
    unsigned* p = (unsigned*)&pk;
#pragma unroll
    for (int jj = 0; jj < 4; ++jj)
      p[jj] = (unsigned)f2bf(t[q * 8 + jj * 2][n]) | ((unsigned)f2bf(t[q * 8 + jj * 2 + 1][n]) << 16);
    *(uint4*)&dst[(size_t)fi * 512 + l * 8] = pk;
  }
}

// ===== fused MT=32, 16 waves/block (R7) ===================================
// R7: double waves/SIMD at constant structure.  grid 512 x 1024 thr:
// 32 waves/CU = 8 waves/SIMD (was 4) for 2x latency hiding.  Per-wave
// tiles halve so block-level work/LDS/weight-traffic/barriers = R4
// exactly.  __launch_bounds__(1024,8) caps VGPR at 64 (tiles sized for
// acc16+A16+B16 ~= 60, no spill expected -- check VGPR/scratch!).
// conv: 2 mg (K-half) x 8 ng (32 cols), 60 steps x 4 MFMA, depth-2 A/B.
// FFN:  2 rg (16 rows) x 8 cg (32 cols) per 256-col chunk, depth-2.
__global__ __launch_bounds__(1024, 8) void k_fused(
    const float* __restrict__ x, const u16* __restrict__ wpk,
    const float* __restrict__ bmix, const float* __restrict__ g1,
    const float* __restrict__ b1, const u16* __restrict__ w1pk,
    const float* __restrict__ bf1, const u16* __restrict__ w2pk,
    const float* __restrict__ bf2, const float* __restrict__ g2,
    const float* __restrict__ b2, float* __restrict__ out)
{
  __shared__ __align__(16) u16 bufA[XR * XPITCH];      // 24.3 KB: xs, then h rows 0..31
  __shared__ __align__(16) u16 asbuf[2 * MT * XPITCH]; // 33.8 KB: fp32 slot / 2x gelu buf
  __shared__ float redS[8][MT], redS2[8][MT];          // 2 KB
  __shared__ float muL[MT], invL[MT];

#define bufB ((float*)asbuf)                       // [MT][SLOTP] conv combine slot

  const int tid = threadIdx.x;
  const int wv = tid >> 6, l = tid & 63, q = l >> 4, cl = l & 15;
  const int mgq = wv >> 3;                         // conv K-half
  const int ng  = wv & 7;                          // conv col group (32 cols)
  const int rg  = wv >> 3;                         // FFN row half (16 rows)
  const int cg  = wv & 7;                          // FFN col group (32 cols)
  const long tok0 = (long)blockIdx.x * MT;
  const int n0 = (int)(tok0 & (NNSEQ - 1));

  // ---- acc init + base pointers hoisted above staging ----
  f32x4 acc[2][2];
#pragma unroll
  for (int nt = 0; nt < 2; ++nt) {
    const float bm = (mgq == 0) ? bmix[ng * 32 + nt * 16 + cl] : 0.f;
#pragma unroll
    for (int mt = 0; mt < 2; ++mt) acc[mt][nt] = (f32x4){bm, bm, bm, bm};
  }
  const u16* bbase = wpk + (size_t)(mgq * 60) * 8192 + (size_t)(ng * 2) * 512 + (size_t)l * 8;

  // ---- stage x rows [tok0-14, tok0+31] as bf16 ----
  {
    const int cslot = l * 4;
    for (int r = wv; r < XR; r += 16) {
      const int nloc = n0 - 14 + r;
      float4 v = make_float4(0.f, 0.f, 0.f, 0.f);
      if (nloc >= 0) v = *(const float4*)&x[(tok0 - 14 + r) * DD + cslot];
      uint2 pk;
      pk.x = (unsigned)f2bf(v.x) | ((unsigned)f2bf(v.y) << 16);
      pk.y = (unsigned)f2bf(v.z) | ((unsigned)f2bf(v.w) << 16);
      *(uint2*)&bufA[r * XPITCH + cslot] = pk;
    }
  }

#define LOAD_A(dst, s_)                                                         \
  {                                                                             \
    const int ks = mgq * 60 + (s_);                                             \
    const int xrow = ks >> 3, c0 = (ks & 7) * 32;                               \
    _Pragma("unroll")                                                           \
    for (int mt = 0; mt < 2; ++mt)                                              \
      dst[mt] = *(const short8*)&bufA[(xrow + mt * 16 + cl) * XPITCH + c0 + q * 8]; \
  }
#define LOAD_B(dst, s_)                                                         \
  {                                                                             \
    const u16* bp = bbase + (size_t)(s_) * 8192;                                \
    _Pragma("unroll")                                                           \
    for (int nt = 0; nt < 2; ++nt)                                              \
      dst[nt] = *(const short8*)(bp + nt * 512);                                \
  }

  // ====== conv GEMM: K-half mgq, cols ng*32.., rows 0..31 (32x32) ========
  // Depth-2 pipeline; B (global) for steps 0..1 issued BEFORE the barrier.
  {
    short8 af[2][2], bfr[2][2];
    LOAD_B(bfr[0], 0)
    LOAD_B(bfr[1], 1)
    __syncthreads();
    LOAD_A(af[0], 0)
    LOAD_A(af[1], 1)

#pragma unroll 2
    for (int s = 0; s < 60; ++s) {
      const int cur = s & 1;
#pragma unroll
      for (int mt = 0; mt < 2; ++mt)
#pragma unroll
        for (int nt = 0; nt < 2; ++nt)
          acc[mt][nt] = MFMA(af[cur][mt], bfr[cur][nt], acc[mt][nt]);
      if (s + 2 < 60) {
        LOAD_A(af[cur], s + 2)
        LOAD_B(bfr[cur], s + 2)
      }
    }
  }
#undef LOAD_A
#undef LOAD_B

  // ---- mg1 -> fp32 slot; mg0 combines + residual + LN1 ----
  if (mgq == 1) {
#pragma unroll
    for (int mt = 0; mt < 2; ++mt)
#pragma unroll
      for (int nt = 0; nt < 2; ++nt)
#pragma unroll
        for (int reg = 0; reg < 4; ++reg)
          bufB[(mt * 16 + q * 4 + reg) * SLOTP + ng * 32 + nt * 16 + cl] = acc[mt][nt][reg];
  }
  __syncthreads();

  if (mgq == 0) {
    float ps[2][4], ps2[2][4];
#pragma unroll
    for (int mt = 0; mt < 2; ++mt)
#pragma unroll
      for (int reg = 0; reg < 4; ++reg) {
        const int row = mt * 16 + q * 4 + reg;
        float s = 0.f, s2 = 0.f;
#pragma unroll
        for (int nt = 0; nt < 2; ++nt) {
          const int col = ng * 32 + nt * 16 + cl;
          const float y = acc[mt][nt][reg] + bufB[row * SLOTP + col]
                        + x[(tok0 + row) * DD + col];        // fp32 residual
          acc[mt][nt][reg] = y;
          s += y; s2 += y * y;
        }
#pragma unroll
        for (int off = 1; off < 16; off <<= 1) { s += __shfl_xor(s, off, 64); s2 += __shfl_xor(s2, off, 64); }
        ps[mt][reg] = s; ps2[mt][reg] = s2;
      }
    if (cl == 0) {
#pragma unroll
      for (int mt = 0; mt < 2; ++mt)
#pragma unroll
        for (int reg = 0; reg < 4; ++reg) {
          const int row = mt * 16 + q * 4 + reg;
          redS[ng][row] = ps[mt][reg]; redS2[ng][row] = ps2[mt][reg];
        }
    }
  }
  __syncthreads();
  if (tid < MT) {
    float s = 0.f, s2 = 0.f;
#pragma unroll
    for (int k = 0; k < 8; ++k) { s += redS[k][tid]; s2 += redS2[k][tid]; }
    const float mu = s * (1.f / DD);
    const float var = s2 * (1.f / DD) - mu * mu;
    muL[tid] = mu; invL[tid] = rsqrtf(var + EPSLN);
  }
  __syncthreads();

  // ---- h (bf16) -> bufA rows 0..31 (mg0 waves, their 32 cols) ----
  if (mgq == 0) {
#pragma unroll
    for (int nt = 0; nt < 2; ++nt) {
      const int col = ng * 32 + nt * 16 + cl;
      const float gv = g1[col], bv = b1[col];
#pragma unroll
      for (int mt = 0; mt < 2; ++mt)
#pragma unroll
        for (int reg = 0; reg < 4; ++reg) {
          const int row = mt * 16 + q * 4 + reg;
          const float hv = (acc[mt][nt][reg] - muL[row]) * invL[row] * gv + bv;
          bufA[row * XPITCH + col] = f2bf(hv);
        }
    }
  }
  __syncthreads();

  // ============ FFN: 4 chunks of 256 H-cols; wave tile 16 x 32 ============
  // wave (rg, cg): rows rg*16.., cols cg*32.. of the chunk.  asb double-
  // buffered by chunk parity: one barrier per chunk; straggler FF2 reads
  // of buffer c&1 overlap next chunk's FF1 writes to (c+1)&1.
  f32x4 acc2[2];
#pragma unroll
  for (int nt = 0; nt < 2; ++nt) {
    const float bv = bf2[cg * 32 + nt * 16 + cl];
    acc2[nt] = (f32x4){bv, bv, bv, bv};
  }

#define FF_LDA(src, dst, s_)                                                    \
    dst = *(const short8*)&src[(rg * 16 + cl) * XPITCH + (s_) * 32 + q * 8];
#define FF_LDB(wsrc, dst, s_)                                                   \
  {                                                                             \
    const u16* bp = wsrc + (size_t)(c * 8 + (s_)) * 8192 + (size_t)(cg * 2) * 512 + (size_t)l * 8; \
    _Pragma("unroll")                                                           \
    for (int nt = 0; nt < 2; ++nt)                                              \
      dst[nt] = *(const short8*)(bp + nt * 512);                                \
  }

  for (int c = 0; c < 4; ++c) {
    u16* asb = asbuf + (c & 1) * (MT * XPITCH);
    // FF1: rows rg*16.. x chunk-cols [cg*32,+32), K = 256
    f32x4 acc1[2];
#pragma unroll
    for (int nt = 0; nt < 2; ++nt) {
      const float bv = bf1[c * 256 + cg * 32 + nt * 16 + cl];
      acc1[nt] = (f32x4){bv, bv, bv, bv};
    }
    {
      short8 a2[2], b2r[2][2];
      FF_LDA(bufA, a2[0], 0) FF_LDB(w1pk, b2r[0], 0)
      FF_LDA(bufA, a2[1], 1) FF_LDB(w1pk, b2r[1], 1)
#pragma unroll
      for (int s = 0; s < 6; ++s) {
        const int cur = s & 1;
#pragma unroll
        for (int nt = 0; nt < 2; ++nt)
          acc1[nt] = MFMA(a2[cur], b2r[cur][nt], acc1[nt]);
        FF_LDA(bufA, a2[cur], s + 2) FF_LDB(w1pk, b2r[cur], s + 2)
      }
#pragma unroll
      for (int s = 6; s < 8; ++s) {
        const int cur = s & 1;
#pragma unroll
        for (int nt = 0; nt < 2; ++nt)
          acc1[nt] = MFMA(a2[cur], b2r[cur][nt], acc1[nt]);
      }
    }
    // fast gelu -> asb (A-layout, chunk-local cols cg*32+nt*16+cl)
#pragma unroll
    for (int nt = 0; nt < 2; ++nt)
#pragma unroll
      for (int reg = 0; reg < 4; ++reg) {
        const float g = fast_gelu(acc1[nt][reg]);
        asb[(rg * 16 + q * 4 + reg) * XPITCH + cg * 32 + nt * 16 + cl] = f2bf(g);
      }
    __syncthreads();
    // FF2: rows rg*16.. x out-cols [cg*32,+32), K = chunk's 256
    {
      short8 a2[2], b2r[2][2];
      FF_LDA(asb, a2[0], 0) FF_LDB(w2pk, b2r[0], 0)
      FF_LDA(asb, a2[1], 1) FF_LDB(w2pk, b2r[1], 1)
#pragma unroll
      for (int s = 0; s < 6; ++s) {
        const int cur = s & 1;
#pragma unroll
        for (int nt = 0; nt < 2; ++nt)
          acc2[nt] = MFMA(a2[cur], b2r[cur][nt], acc2[nt]);
        FF_LDA(asb, a2[cur], s + 2) FF_LDB(w2pk, b2r[cur], s + 2)
      }
#pragma unroll
      for (int s = 6; s < 8; ++s) {
        const int cur = s & 1;
#pragma unroll
        for (int nt = 0; nt < 2; ++nt)
          acc2[nt] = MFMA(a2[cur], b2r[cur][nt], acc2[nt]);
      }
    }
    // no trailing barrier: next chunk writes the other asb buffer
  }
#undef FF_LDA
#undef FF_LDB

  // ---- residual (h from bufA) + LN2 ----
  {
    float ps[4], ps2[4];
#pragma unroll
    for (int reg = 0; reg < 4; ++reg) {
      const int row = rg * 16 + q * 4 + reg;
      float s = 0.f, s2 = 0.f;
#pragma unroll
      for (int nt = 0; nt < 2; ++nt) {
        const int col = cg * 32 + nt * 16 + cl;
        const float y = acc2[nt][reg] + bf2f(bufA[row * XPITCH + col]);
        acc2[nt][reg] = y;
        s += y; s2 += y * y;
      }
#pragma unroll
      for (int off = 1; off < 16; off <<= 1) { s += __shfl_xor(s, off, 64); s2 += __shfl_xor(s2, off, 64); }
      ps[reg] = s; ps2[reg] = s2;
    }
    if (cl == 0) {
#pragma unroll
      for (int reg = 0; reg < 4; ++reg) {
        const int row = rg * 16 + q * 4 + reg;
        redS[cg][row] = ps[reg]; redS2[cg][row] = ps2[reg];
      }
    }
  }
  __syncthreads();
  if (tid < MT) {
    float s = 0.f, s2 = 0.f;
#pragma unroll
    for (int k = 0; k < 8; ++k) { s += redS[k][tid]; s2 += redS2[k][tid]; }
    const float mu = s * (1.f / DD);
    const float var = s2 * (1.f / DD) - mu * mu;
    muL[tid] = mu; invL[tid] = rsqrtf(var + EPSLN);
  }
  __syncthreads();

#pragma unroll
  for (int nt = 0; nt < 2; ++nt) {
    const int col = cg * 32 + nt * 16 + cl;
    const float gv = g2[col], bv = b2[col];
#pragma unroll
    for (int reg = 0; reg < 4; ++reg) {
      const int row = rg * 16 + q * 4 + reg;
      out[(tok0 + row) * DD + col] = (acc2[nt][reg] - muL[row]) * invL[row] * gv + bv;
    }
  }
#undef bufB
}

// ---------------- launch ----------------
extern "C" void kernel_launch(void* const* d_in, const int* in_sizes, int n_in,
                              void* d_out, int out_size, void* d_ws, size_t ws_size,
                              hipStream_t stream) {
  const float* x    = (const float*)d_in[0];
  const float* wmix = (const float*)d_in[1];   // [3840][256]
  const float* bmix = (const float*)d_in[2];
  const float* g1   = (const float*)d_in[3];
  const float* b1   = (const float*)d_in[4];
  const float* wff1 = (const float*)d_in[5];   // [256][1024]
  const float* bff1 = (const float*)d_in[6];
  const float* wff2 = (const float*)d_in[7];   // [1024][256]
  const float* bff2 = (const float*)d_in[8];
  const float* g2   = (const float*)d_in[9];
  const float* b2   = (const float*)d_in[10];
  float* out = (float*)d_out;

  u16* wpk  = (u16*)d_ws;                // 120*8192 = 983040 elems (1.97 MB)
  u16* w1pk = wpk + 983040;              // 32*8192 = 262144
  u16* w2pk = w1pk + 262144;             // 262144

  k_prep<<<184, 256, 0, stream>>>(wmix, wff1, wff2, wpk, w1pk, w2pk);

  k_fused<<<512, 1024, 0, stream>>>(x, wpk, bmix, g1, b1,
                                    w1pk, bff1, w2pk, bff2, g2, b2, out);
}

// Round 8
// 153.538 us; speedup vs baseline: 1.1005x; 1.1005x over previous
//
#include <hip/hip_runtime.h>
#include <cstdint>

// ---------------- problem constants ----------------
#define DD     256
#define HH     1024
#define NNSEQ  4096
#define MT     32            // tokens per block (grid 512 = 2 blocks/CU)
#define XR     46            // MT + 14 halo rows
#define XPITCH 264           // 256 + 8 pad (bf16 elems), row 528 B
#define SLOTP  260           // fp32 slot pitch
#define EPSLN  1e-5f

typedef unsigned short u16;
typedef __attribute__((ext_vector_type(8))) short short8;
typedef __attribute__((ext_vector_type(4))) float f32x4;

#define MFMA(a, b, c) __builtin_amdgcn_mfma_f32_16x16x32_bf16(a, b, c, 0, 0, 0)

__device__ __forceinline__ u16 f2bf(float f) {           // RNE fp32 -> bf16
  unsigned u = __float_as_uint(f);
  u += 0x7FFF + ((u >> 16) & 1);
  return (u16)(u >> 16);
}
__device__ __forceinline__ float bf2f(u16 s) { return __uint_as_float(((unsigned)s) << 16); }

// tanh-form GELU via sigmoid identity: 0.5v(1+tanh(u)) = v*sigmoid(2u).
// Max |err| vs exact erf-GELU ~3e-4, under the bf16 quantization applied after.
__device__ __forceinline__ float fast_gelu(float v) {
  const float e = __expf(v * __builtin_fmaf(v * v, -0.0713548163f, -1.5957691216f));
  return v * __builtin_amdgcn_rcpf(1.f + e);
}

// ======== prep R8: fully-parallel direct pack (no LDS, no syncthreads) ====
// One thread per 8-element output fragment: 184 slabs x 1024 thr = 188,416
// threads (736 blocks).  Old version: 184 blocks (0.7/CU), serial 32-row
// stage + barrier + strided repack per block -- a long latency chain with
// no co-resident waves to hide it (suspected ~70 us of the harness total).
// Packing math identical: dst[fi*512 + l*8 + j] = W[K = s*32 + (l>>4)*8 + j]
// [n = fi*16 + (l&15)], RNE fp32->bf16 -- bit-identical output.
__global__ __launch_bounds__(256) void k_prep(
    const float* __restrict__ wmix, const float* __restrict__ wff1,
    const float* __restrict__ wff2, u16* __restrict__ wpk,
    u16* __restrict__ w1pk, u16* __restrict__ w2pk)
{
  const int g = blockIdx.x * 256 + threadIdx.x;
  const int u = g >> 10;                 // slab 0..183 (uniform per block)
  const int t = g & 1023;                // fragment within slab
  const int fi = t >> 6, l = t & 63, q = l >> 4, cl = l & 15;
  const int n = fi * 16 + cl;            // output column
  const int r0 = q * 8;                  // first of 8 K-rows

  const float* src;
  int rowstride;
  u16* dst;
  if (u < 120) {                                   // conv slab s = u
    src = wmix + (size_t)(u * 32 + r0) * 256 + n;
    rowstride = 256;
    dst = wpk + (size_t)u * 8192;
  } else if (u < 152) {                            // FF1: u' = c2*8+s
    const int v = u - 120, c2 = v >> 3, s = v & 7;
    src = wff1 + (size_t)(s * 32 + r0) * 1024 + c2 * 256 + n;
    rowstride = 1024;
    dst = w1pk + (size_t)v * 8192;
  } else {                                         // FF2: u' = c2*8+s
    const int v = u - 152, c2 = v >> 3, s = v & 7;
    src = wff2 + (size_t)(c2 * 256 + s * 32 + r0) * 256 + n;
    rowstride = 256;
    dst = w2pk + (size_t)v * 8192;
  }

  float w[8];
#pragma unroll
  for (int j = 0; j < 8; ++j) w[j] = src[(size_t)j * rowstride];

  uint4 pk;
  unsigned* p = (unsigned*)&pk;
#pragma unroll
  for (int jj = 0; jj < 4; ++jj)
    p[jj] = (unsigned)f2bf(w[jj * 2]) | ((unsigned)f2bf(w[jj * 2 + 1]) << 16);
  *(uint4*)&dst[(size_t)fi * 512 + (size_t)l * 8] = pk;
}

// ===== fused: conv(mg K-split) + LN1 + FFN + LN2, MT=32, 2 blocks/CU =====
// EXACT R4 champion (76.6 us): depth-3 conv pipeline with B-issue hoisted
// above the staging barrier, FF1/FF2 depth-2 A/B double-buffer, fast_gelu,
// asb chunk-parity double-buffer.  Unchanged this round so the k_prep
// delta is cleanly attributable.
__global__ __launch_bounds__(512, 4) void k_fused(
    const float* __restrict__ x, const u16* __restrict__ wpk,
    const float* __restrict__ bmix, const float* __restrict__ g1,
    const float* __restrict__ b1, const u16* __restrict__ w1pk,
    const float* __restrict__ bf1, const u16* __restrict__ w2pk,
    const float* __restrict__ bf2, const float* __restrict__ g2,
    const float* __restrict__ b2, float* __restrict__ out)
{
  __shared__ __align__(16) u16 bufA[XR * XPITCH];      // 24.3 KB: xs, then h rows 0..31
  __shared__ __align__(16) u16 asbuf[2 * MT * XPITCH]; // 33.8 KB: fp32 slot / 2x gelu buf
  __shared__ float redS[8][MT], redS2[8][MT];          // 2 KB
  __shared__ float muL[MT], invL[MT];

#define bufB ((float*)asbuf)                       // [MT][SLOTP] conv combine slot

  const int tid = threadIdx.x;
  const int wv = tid >> 6, l = tid & 63, q = l >> 4, cl = l & 15;
  const int mg = wv >> 2, ng = wv & 3;
  const long tok0 = (long)blockIdx.x * MT;
  const int n0 = (int)(tok0 & (NNSEQ - 1));

  // ---- acc init + base pointers hoisted above staging (overlaps) ----
  f32x4 acc[2][4];
#pragma unroll
  for (int nt = 0; nt < 4; ++nt) {
    const float bm = (mg == 0) ? bmix[ng * 64 + nt * 16 + cl] : 0.f;
#pragma unroll
    for (int mt = 0; mt < 2; ++mt) acc[mt][nt] = (f32x4){bm, bm, bm, bm};
  }
  const u16* bbase = wpk + (size_t)(mg * 60) * 8192 + (size_t)(ng * 4) * 512 + (size_t)l * 8;

  // ---- stage x rows [tok0-14, tok0+31] as bf16 ----
  {
    const int cslot = l * 4;
    for (int r = wv; r < XR; r += 8) {
      const int nloc = n0 - 14 + r;
      float4 v = make_float4(0.f, 0.f, 0.f, 0.f);
      if (nloc >= 0) v = *(const float4*)&x[(tok0 - 14 + r) * DD + cslot];
      uint2 pk;
      pk.x = (unsigned)f2bf(v.x) | ((unsigned)f2bf(v.y) << 16);
      pk.y = (unsigned)f2bf(v.z) | ((unsigned)f2bf(v.w) << 16);
      *(uint2*)&bufA[r * XPITCH + cslot] = pk;
    }
  }

#define LOAD_A(dst, s_)                                                         \
  {                                                                             \
    const int ks = mg * 60 + (s_);                                              \
    const int xrow = ks >> 3, c0 = (ks & 7) * 32;                               \
    _Pragma("unroll")                                                           \
    for (int mt = 0; mt < 2; ++mt)                                              \
      dst[mt] = *(const short8*)&bufA[(xrow + mt * 16 + cl) * XPITCH + c0 + q * 8]; \
  }
#define LOAD_B(dst, s_)                                                         \
  {                                                                             \
    const u16* bp = bbase + (size_t)(s_) * 8192;                                \
    _Pragma("unroll")                                                           \
    for (int nt = 0; nt < 4; ++nt)                                              \
      dst[nt] = *(const short8*)(bp + nt * 512);                                \
  }

  // ================= conv GEMM: K-half mg, cols ng*64.., 32 rows ========
  // Depth-3 pipeline; B (global) for steps 0..2 issued BEFORE the barrier
  // so the L2 latency hides under staging + barrier wait.
  {
    short8 af[3][2], bfr[3][4];
    LOAD_B(bfr[0], 0)
    LOAD_B(bfr[1], 1)
    LOAD_B(bfr[2], 2)
    __syncthreads();
    LOAD_A(af[0], 0)
    LOAD_A(af[1], 1)
    LOAD_A(af[2], 2)

    for (int sb = 0; sb < 57; sb += 3) {
#pragma unroll
      for (int u = 0; u < 3; ++u) {
#pragma unroll
        for (int mt = 0; mt < 2; ++mt)
#pragma unroll
          for (int nt = 0; nt < 4; ++nt)
            acc[mt][nt] = MFMA(af[u][mt], bfr[u][nt], acc[mt][nt]);
        LOAD_A(af[u], sb + u + 3)
        LOAD_B(bfr[u], sb + u + 3)
      }
    }
#pragma unroll
    for (int u = 0; u < 3; ++u) {                  // tail: steps 57..59
#pragma unroll
      for (int mt = 0; mt < 2; ++mt)
#pragma unroll
        for (int nt = 0; nt < 4; ++nt)
          acc[mt][nt] = MFMA(af[u][mt], bfr[u][nt], acc[mt][nt]);
    }
  }
#undef LOAD_A
#undef LOAD_B

  // ---- mg1 -> fp32 slot; mg0 combines + residual + LN1 ----
  if (mg == 1) {
#pragma unroll
    for (int mt = 0; mt < 2; ++mt)
#pragma unroll
      for (int nt = 0; nt < 4; ++nt)
#pragma unroll
        for (int reg = 0; reg < 4; ++reg)
          bufB[(mt * 16 + q * 4 + reg) * SLOTP + ng * 64 + nt * 16 + cl] = acc[mt][nt][reg];
  }
  __syncthreads();

  if (mg == 0) {
    float ps[2][4], ps2[2][4];
#pragma unroll
    for (int mt = 0; mt < 2; ++mt)
#pragma unroll
      for (int reg = 0; reg < 4; ++reg) {
        const int row = mt * 16 + q * 4 + reg;
        float s = 0.f, s2 = 0.f;
#pragma unroll
        for (int nt = 0; nt < 4; ++nt) {
          const int col = ng * 64 + nt * 16 + cl;
          const float y = acc[mt][nt][reg] + bufB[row * SLOTP + col]
                        + x[(tok0 + row) * DD + col];        // fp32 residual
          acc[mt][nt][reg] = y;
          s += y; s2 += y * y;
        }
#pragma unroll
        for (int off = 1; off < 16; off <<= 1) { s += __shfl_xor(s, off, 64); s2 += __shfl_xor(s2, off, 64); }
        ps[mt][reg] = s; ps2[mt][reg] = s2;
      }
    if (cl == 0) {
#pragma unroll
      for (int mt = 0; mt < 2; ++mt)
#pragma unroll
        for (int reg = 0; reg < 4; ++reg) {
          const int row = mt * 16 + q * 4 + reg;
          redS[ng][row] = ps[mt][reg]; redS2[ng][row] = ps2[mt][reg];
        }
    }
  }
  __syncthreads();
  if (tid < MT) {
    const float s  = redS[0][tid] + redS[1][tid] + redS[2][tid] + redS[3][tid];
    const float s2 = redS2[0][tid] + redS2[1][tid] + redS2[2][tid] + redS2[3][tid];
    const float mu = s * (1.f / DD);
    const float var = s2 * (1.f / DD) - mu * mu;
    muL[tid] = mu; invL[tid] = rsqrtf(var + EPSLN);
  }
  __syncthreads();

  // ---- h (bf16) -> bufA rows 0..31 ----
  if (mg == 0) {
#pragma unroll
    for (int nt = 0; nt < 4; ++nt) {
      const int col = ng * 64 + nt * 16 + cl;
      const float gv = g1[col], bv = b1[col];
#pragma unroll
      for (int mt = 0; mt < 2; ++mt)
#pragma unroll
        for (int reg = 0; reg < 4; ++reg) {
          const int row = mt * 16 + q * 4 + reg;
          const float hv = (acc[mt][nt][reg] - muL[row]) * invL[row] * gv + bv;
          bufA[row * XPITCH + col] = f2bf(hv);
        }
    }
  }
  __syncthreads();

  // ============ FFN: 4 chunks of 256 H-cols; wave tile 32 x 32 ============
  // asb double-buffered by chunk parity (one barrier per chunk).  FF1/FF2
  // inner loops: explicit depth-2 A/B double-buffer, peeled 2-step tails.
  f32x4 acc2[2][2];
#pragma unroll
  for (int nt = 0; nt < 2; ++nt) {
    const float bv = bf2[wv * 32 + nt * 16 + cl];
#pragma unroll
    for (int mt = 0; mt < 2; ++mt) acc2[mt][nt] = (f32x4){bv, bv, bv, bv};
  }

#define FF_LDA(src, dst, s_)                                                    \
  {                                                                             \
    _Pragma("unroll")                                                           \
    for (int mt = 0; mt < 2; ++mt)                                              \
      dst[mt] = *(const short8*)&src[(mt * 16 + cl) * XPITCH + (s_) * 32 + q * 8]; \
  }
#define FF_LDB(wsrc, dst, s_)                                                   \
  {                                                                             \
    const u16* bp = wsrc + (size_t)(c * 8 + (s_)) * 8192 + (size_t)(wv * 2) * 512 + (size_t)l * 8; \
    _Pragma("unroll")                                                           \
    for (int nt = 0; nt < 2; ++nt)                                              \
      dst[nt] = *(const short8*)(bp + nt * 512);                                \
  }

  for (int c = 0; c < 4; ++c) {
    u16* asb = asbuf + (c & 1) * (MT * XPITCH);
    // FF1: rows 0..31 (mt) x chunk-cols [wv*32,+32), K = 256
    f32x4 acc1[2][2];
#pragma unroll
    for (int nt = 0; nt < 2; ++nt) {
      const float bv = bf1[c * 256 + wv * 32 + nt * 16 + cl];
#pragma unroll
      for (int mt = 0; mt < 2; ++mt) acc1[mt][nt] = (f32x4){bv, bv, bv, bv};
    }
    {
      short8 a2[2][2], b2r[2][2];
      FF_LDA(bufA, a2[0], 0) FF_LDB(w1pk, b2r[0], 0)
      FF_LDA(bufA, a2[1], 1) FF_LDB(w1pk, b2r[1], 1)
#pragma unroll
      for (int s = 0; s < 6; ++s) {
        const int cur = s & 1;
#pragma unroll
        for (int mt = 0; mt < 2; ++mt)
#pragma unroll
          for (int nt = 0; nt < 2; ++nt)
            acc1[mt][nt] = MFMA(a2[cur][mt], b2r[cur][nt], acc1[mt][nt]);
        FF_LDA(bufA, a2[cur], s + 2) FF_LDB(w1pk, b2r[cur], s + 2)
      }
#pragma unroll
      for (int s = 6; s < 8; ++s) {
        const int cur = s & 1;
#pragma unroll
        for (int mt = 0; mt < 2; ++mt)
#pragma unroll
          for (int nt = 0; nt < 2; ++nt)
            acc1[mt][nt] = MFMA(a2[cur][mt], b2r[cur][nt], acc1[mt][nt]);
      }
    }
    // fast gelu -> asb (A-layout, chunk-local cols wv*32+nt*16+cl)
#pragma unroll
    for (int mt = 0; mt < 2; ++mt)
#pragma unroll
      for (int nt = 0; nt < 2; ++nt)
#pragma unroll
        for (int reg = 0; reg < 4; ++reg) {
          const float g = fast_gelu(acc1[mt][nt][reg]);
          asb[(mt * 16 + q * 4 + reg) * XPITCH + wv * 32 + nt * 16 + cl] = f2bf(g);
        }
    __syncthreads();
    // FF2: rows 0..31 x out-cols [wv*32,+32), K = chunk's 256
    {
      short8 a2[2][2], b2r[2][2];
      FF_LDA(asb, a2[0], 0) FF_LDB(w2pk, b2r[0], 0)
      FF_LDA(asb, a2[1], 1) FF_LDB(w2pk, b2r[1], 1)
#pragma unroll
      for (int s = 0; s < 6; ++s) {
        const int cur = s & 1;
#pragma unroll
        for (int mt = 0; mt < 2; ++mt)
#pragma unroll
          for (int nt = 0; nt < 2; ++nt)
            acc2[mt][nt] = MFMA(a2[cur][mt], b2r[cur][nt], acc2[mt][nt]);
        FF_LDA(asb, a2[cur], s + 2) FF_LDB(w2pk, b2r[cur], s + 2)
      }
#pragma unroll
      for (int s = 6; s < 8; ++s) {
        const int cur = s & 1;
#pragma unroll
        for (int mt = 0; mt < 2; ++mt)
#pragma unroll
          for (int nt = 0; nt < 2; ++nt)
            acc2[mt][nt] = MFMA(a2[cur][mt], b2r[cur][nt], acc2[mt][nt]);
      }
    }
    // no trailing barrier: next chunk writes the other asb buffer
  }
#undef FF_LDA
#undef FF_LDB

  // ---- residual (h from bufA) + LN2 ----
  {
    float ps[2][4], ps2[2][4];
#pragma unroll
    for (int mt = 0; mt < 2; ++mt)
#pragma unroll
      for (int reg = 0; reg < 4; ++reg) {
        const int row = mt * 16 + q * 4 + reg;
        float s = 0.f, s2 = 0.f;
#pragma unroll
        for (int nt = 0; nt < 2; ++nt) {
          const int col = wv * 32 + nt * 16 + cl;
          const float y = acc2[mt][nt][reg] + bf2f(bufA[row * XPITCH + col]);
          acc2[mt][nt][reg] = y;
          s += y; s2 += y * y;
        }
#pragma unroll
        for (int off = 1; off < 16; off <<= 1) { s += __shfl_xor(s, off, 64); s2 += __shfl_xor(s2, off, 64); }
        ps[mt][reg] = s; ps2[mt][reg] = s2;
      }
    if (cl == 0) {
#pragma unroll
      for (int mt = 0; mt < 2; ++mt)
#pragma unroll
        for (int reg = 0; reg < 4; ++reg) {
          const int row = mt * 16 + q * 4 + reg;
          redS[wv][row] = ps[mt][reg]; redS2[wv][row] = ps2[mt][reg];
        }
    }
  }
  __syncthreads();
  if (tid < MT) {
    float s = 0.f, s2 = 0.f;
#pragma unroll
    for (int k = 0; k < 8; ++k) { s += redS[k][tid]; s2 += redS2[k][tid]; }
    const float mu = s * (1.f / DD);
    const float var = s2 * (1.f / DD) - mu * mu;
    muL[tid] = mu; invL[tid] = rsqrtf(var + EPSLN);
  }
  __syncthreads();

#pragma unroll
  for (int nt = 0; nt < 2; ++nt) {
    const int col = wv * 32 + nt * 16 + cl;
    const float gv = g2[col], bv = b2[col];
#pragma unroll
    for (int mt = 0; mt < 2; ++mt)
#pragma unroll
      for (int reg = 0; reg < 4; ++reg) {
        const int row = mt * 16 + q * 4 + reg;
        out[(tok0 + row) * DD + col] = (acc2[mt][nt][reg] - muL[row]) * invL[row] * gv + bv;
      }
  }
#undef bufB
}

// ---------------- launch ----------------
extern "C" void kernel_launch(void* const* d_in, const int* in_sizes, int n_in,
                              void* d_out, int out_size, void* d_ws, size_t ws_size,
                              hipStream_t stream) {
  const float* x    = (const float*)d_in[0];
  const float* wmix = (const float*)d_in[1];   // [3840][256]
  const float* bmix = (const float*)d_in[2];
  const float* g1   = (const float*)d_in[3];
  const float* b1   = (const float*)d_in[4];
  const float* wff1 = (const float*)d_in[5];   // [256][1024]
  const float* bff1 = (const float*)d_in[6];
  const float* wff2 = (const float*)d_in[7];   // [1024][256]
  const float* bff2 = (const float*)d_in[8];
  const float* g2   = (const float*)d_in[9];
  const float* b2   = (const float*)d_in[10];
  float* out = (float*)d_out;

  u16* wpk  = (u16*)d_ws;                // 120*8192 = 983040 elems (1.97 MB)
  u16* w1pk = wpk + 983040;              // 32*8192 = 262144
  u16* w2pk = w1pk + 262144;             // 262144

  // 184 slabs x 1024 fragments-of-8 = 188416 threads = 736 x 256
  k_prep<<<736, 256, 0, stream>>>(wmix, wff1, wff2, wpk, w1pk, w2pk);

  k_fused<<<512, 512, 0, stream>>>(x, wpk, bmix, g1, b1,
                                   w1pk, bff1, w2pk, bff2, g2, b2, out);
}

// Round 10
// 150.777 us; speedup vs baseline: 1.1206x; 1.0183x over previous
//
#include <hip/hip_runtime.h>
#include <cstdint>

// ---------------- problem constants ----------------
#define DD     256
#define HH     1024
#define NNSEQ  4096
#define MT     32            // tokens per block (grid 512 = 2 blocks/CU)
#define XR     46            // MT + 14 halo rows
#define XPITCH 264           // 256 + 8 pad (bf16 elems), row 528 B
#define SLOTP  260           // fp32 slot pitch
#define EPSLN  1e-5f

typedef unsigned short u16;
typedef __attribute__((ext_vector_type(8))) short short8;
typedef __attribute__((ext_vector_type(4))) float f32x4;

#define MFMA(a, b, c) __builtin_amdgcn_mfma_f32_16x16x32_bf16(a, b, c, 0, 0, 0)

__device__ __forceinline__ u16 f2bf(float f) {           // RNE fp32 -> bf16
  unsigned u = __float_as_uint(f);
  u += 0x7FFF + ((u >> 16) & 1);
  return (u16)(u >> 16);
}
__device__ __forceinline__ float bf2f(u16 s) { return __uint_as_float(((unsigned)s) << 16); }

// tanh-form GELU via sigmoid identity: 0.5v(1+tanh(u)) = v*sigmoid(2u).
// Max |err| vs exact erf-GELU ~3e-4, under the bf16 quantization applied after.
__device__ __forceinline__ float fast_gelu(float v) {
  const float e = __expf(v * __builtin_fmaf(v * v, -0.0713548163f, -1.5957691216f));
  return v * __builtin_amdgcn_rcpf(1.f + e);
}

// ======== prep: fully-parallel direct pack (R8, ~1 us) ====================
// One thread per 8-element output fragment: 184 slabs x 1024 thr.
// dst[fi*512 + l*8 + j] = W[K = s*32 + (l>>4)*8 + j][n = fi*16 + (l&15)]
__global__ __launch_bounds__(256) void k_prep(
    const float* __restrict__ wmix, const float* __restrict__ wff1,
    const float* __restrict__ wff2, u16* __restrict__ wpk,
    u16* __restrict__ w1pk, u16* __restrict__ w2pk)
{
  const int g = blockIdx.x * 256 + threadIdx.x;
  const int u = g >> 10;                 // slab 0..183 (uniform per block)
  const int t = g & 1023;                // fragment within slab
  const int fi = t >> 6, l = t & 63, q = l >> 4, cl = l & 15;
  const int n = fi * 16 + cl;            // output column
  const int r0 = q * 8;                  // first of 8 K-rows

  const float* src;
  int rowstride;
  u16* dst;
  if (u < 120) {                                   // conv slab s = u
    src = wmix + (size_t)(u * 32 + r0) * 256 + n;
    rowstride = 256;
    dst = wpk + (size_t)u * 8192;
  } else if (u < 152) {                            // FF1: u' = c2*8+s
    const int v = u - 120, c2 = v >> 3, s = v & 7;
    src = wff1 + (size_t)(s * 32 + r0) * 1024 + c2 * 256 + n;
    rowstride = 1024;
    dst = w1pk + (size_t)v * 8192;
  } else {                                         // FF2: u' = c2*8+s
    const int v = u - 152, c2 = v >> 3, s = v & 7;
    src = wff2 + (size_t)(c2 * 256 + s * 32 + r0) * 256 + n;
    rowstride = 256;
    dst = w2pk + (size_t)v * 8192;
  }

  float w[8];
#pragma unroll
  for (int j = 0; j < 8; ++j) w[j] = src[(size_t)j * rowstride];

  uint4 pk;
  unsigned* p = (unsigned*)&pk;
#pragma unroll
  for (int jj = 0; jj < 4; ++jj)
    p[jj] = (unsigned)f2bf(w[jj * 2]) | ((unsigned)f2bf(w[jj * 2 + 1]) << 16);
  *(uint4*)&dst[(size_t)fi * 512 + (size_t)l * 8] = pk;
}

// ===== fused: conv(mg K-split) + LN1 + FFN + LN2, MT=32, 2 blocks/CU =====
// R9 (on R4 champion): latency/arbitration pass.
//  - s_setprio(1) around MFMA bursts (2 independent blocks/CU at different
//    phases -> scheduler favors the MFMA-heavy wave, attn-analog +4-7%).
//  - x-residual prefetch before the slot barrier (hides ~200cy L2 latency
//    previously exposed right after the barrier).
//  - cross-phase weight prefetch: FF2-B before gelu+barrier; next-chunk
//    FF1-B before the chunk barrier; chunk-0 FF1-B before h-write barrier.
//    (Compiler cannot hoist global loads across __syncthreads itself.)
__global__ __launch_bounds__(512, 4) void k_fused(
    const float* __restrict__ x, const u16* __restrict__ wpk,
    const float* __restrict__ bmix, const float* __restrict__ g1,
    const float* __restrict__ b1, const u16* __restrict__ w1pk,
    const float* __restrict__ bf1, const u16* __restrict__ w2pk,
    const float* __restrict__ bf2, const float* __restrict__ g2,
    const float* __restrict__ b2, float* __restrict__ out)
{
  __shared__ __align__(16) u16 bufA[XR * XPITCH];      // 24.3 KB: xs, then h rows 0..31
  __shared__ __align__(16) u16 asbuf[2 * MT * XPITCH]; // 33.8 KB: fp32 slot / 2x gelu buf
  __shared__ float redS[8][MT], redS2[8][MT];          // 2 KB
  __shared__ float muL[MT], invL[MT];

#define bufB ((float*)asbuf)                       // [MT][SLOTP] conv combine slot

  const int tid = threadIdx.x;
  const int wv = tid >> 6, l = tid & 63, q = l >> 4, cl = l & 15;
  const int mg = wv >> 2, ng = wv & 3;
  const long tok0 = (long)blockIdx.x * MT;
  const int n0 = (int)(tok0 & (NNSEQ - 1));

  // ---- acc init + base pointers hoisted above staging (overlaps) ----
  f32x4 acc[2][4];
#pragma unroll
  for (int nt = 0; nt < 4; ++nt) {
    const float bm = (mg == 0) ? bmix[ng * 64 + nt * 16 + cl] : 0.f;
#pragma unroll
    for (int mt = 0; mt < 2; ++mt) acc[mt][nt] = (f32x4){bm, bm, bm, bm};
  }
  const u16* bbase = wpk + (size_t)(mg * 60) * 8192 + (size_t)(ng * 4) * 512 + (size_t)l * 8;

  // ---- stage x rows [tok0-14, tok0+31] as bf16 ----
  {
    const int cslot = l * 4;
    for (int r = wv; r < XR; r += 8) {
      const int nloc = n0 - 14 + r;
      float4 v = make_float4(0.f, 0.f, 0.f, 0.f);
      if (nloc >= 0) v = *(const float4*)&x[(tok0 - 14 + r) * DD + cslot];
      uint2 pk;
      pk.x = (unsigned)f2bf(v.x) | ((unsigned)f2bf(v.y) << 16);
      pk.y = (unsigned)f2bf(v.z) | ((unsigned)f2bf(v.w) << 16);
      *(uint2*)&bufA[r * XPITCH + cslot] = pk;
    }
  }

#define LOAD_A(dst, s_)                                                         \
  {                                                                             \
    const int ks = mg * 60 + (s_);                                              \
    const int xrow = ks >> 3, c0 = (ks & 7) * 32;                               \
    _Pragma("unroll")                                                           \
    for (int mt = 0; mt < 2; ++mt)                                              \
      dst[mt] = *(const short8*)&bufA[(xrow + mt * 16 + cl) * XPITCH + c0 + q * 8]; \
  }
#define LOAD_B(dst, s_)                                                         \
  {                                                                             \
    const u16* bp = bbase + (size_t)(s_) * 8192;                                \
    _Pragma("unroll")                                                           \
    for (int nt = 0; nt < 4; ++nt)                                              \
      dst[nt] = *(const short8*)(bp + nt * 512);                                \
  }

  // ================= conv GEMM: K-half mg, cols ng*64.., 32 rows ========
  // Depth-3 pipeline; B (global) for steps 0..2 issued BEFORE the barrier
  // so the L2 latency hides under staging + barrier wait.
  {
    short8 af[3][2], bfr[3][4];
    LOAD_B(bfr[0], 0)
    LOAD_B(bfr[1], 1)
    LOAD_B(bfr[2], 2)
    __syncthreads();
    LOAD_A(af[0], 0)
    LOAD_A(af[1], 1)
    LOAD_A(af[2], 2)

    for (int sb = 0; sb < 57; sb += 3) {
#pragma unroll
      for (int u = 0; u < 3; ++u) {
        __builtin_amdgcn_s_setprio(1);
#pragma unroll
        for (int mt = 0; mt < 2; ++mt)
#pragma unroll
          for (int nt = 0; nt < 4; ++nt)
            acc[mt][nt] = MFMA(af[u][mt], bfr[u][nt], acc[mt][nt]);
        __builtin_amdgcn_s_setprio(0);
        LOAD_A(af[u], sb + u + 3)
        LOAD_B(bfr[u], sb + u + 3)
      }
    }
#pragma unroll
    for (int u = 0; u < 3; ++u) {                  // tail: steps 57..59
      __builtin_amdgcn_s_setprio(1);
#pragma unroll
      for (int mt = 0; mt < 2; ++mt)
#pragma unroll
        for (int nt = 0; nt < 4; ++nt)
          acc[mt][nt] = MFMA(af[u][mt], bfr[u][nt], acc[mt][nt]);
      __builtin_amdgcn_s_setprio(0);
    }
  }
#undef LOAD_A
#undef LOAD_B

  // ---- x-residual prefetch (mg0): issue BEFORE the slot barrier so the
  // ~200cy L2 latency hides under mg1's slot stores + barrier wait ----
  float xres[2][4][4];
  if (mg == 0) {
#pragma unroll
    for (int mt = 0; mt < 2; ++mt)
#pragma unroll
      for (int reg = 0; reg < 4; ++reg) {
        const int row = mt * 16 + q * 4 + reg;
        const float* xp = &x[(tok0 + row) * DD + ng * 64 + cl];
#pragma unroll
        for (int nt = 0; nt < 4; ++nt) xres[mt][reg][nt] = xp[nt * 16];
      }
  }

  // ---- mg1 -> fp32 slot; mg0 combines + residual + LN1 ----
  if (mg == 1) {
#pragma unroll
    for (int mt = 0; mt < 2; ++mt)
#pragma unroll
      for (int nt = 0; nt < 4; ++nt)
#pragma unroll
        for (int reg = 0; reg < 4; ++reg)
          bufB[(mt * 16 + q * 4 + reg) * SLOTP + ng * 64 + nt * 16 + cl] = acc[mt][nt][reg];
  }
  __syncthreads();

  if (mg == 0) {
    float ps[2][4], ps2[2][4];
#pragma unroll
    for (int mt = 0; mt < 2; ++mt)
#pragma unroll
      for (int reg = 0; reg < 4; ++reg) {
        const int row = mt * 16 + q * 4 + reg;
        float s = 0.f, s2 = 0.f;
#pragma unroll
        for (int nt = 0; nt < 4; ++nt) {
          const int col = ng * 64 + nt * 16 + cl;
          const float y = acc[mt][nt][reg] + bufB[row * SLOTP + col]
                        + xres[mt][reg][nt];                 // fp32 residual
          acc[mt][nt][reg] = y;
          s += y; s2 += y * y;
        }
#pragma unroll
        for (int off = 1; off < 16; off <<= 1) { s += __shfl_xor(s, off, 64); s2 += __shfl_xor(s2, off, 64); }
        ps[mt][reg] = s; ps2[mt][reg] = s2;
      }
    if (cl == 0) {
#pragma unroll
      for (int mt = 0; mt < 2; ++mt)
#pragma unroll
        for (int reg = 0; reg < 4; ++reg) {
          const int row = mt * 16 + q * 4 + reg;
          redS[ng][row] = ps[mt][reg]; redS2[ng][row] = ps2[mt][reg];
        }
    }
  }
  __syncthreads();
  if (tid < MT) {
    const float s  = redS[0][tid] + redS[1][tid] + redS[2][tid] + redS[3][tid];
    const float s2 = redS2[0][tid] + redS2[1][tid] + redS2[2][tid] + redS2[3][tid];
    const float mu = s * (1.f / DD);
    const float var = s2 * (1.f / DD) - mu * mu;
    muL[tid] = mu; invL[tid] = rsqrtf(var + EPSLN);
  }
  __syncthreads();

#define FF_LDB(wsrc, dst, c_, s_)                                               \
  {                                                                             \
    const u16* bp = wsrc + (size_t)((c_) * 8 + (s_)) * 8192 + (size_t)(wv * 2) * 512 + (size_t)l * 8; \
    _Pragma("unroll")                                                           \
    for (int nt = 0; nt < 2; ++nt)                                              \
      dst[nt] = *(const short8*)(bp + nt * 512);                                \
  }
#define FF_LDA(src, dst, s_)                                                    \
  {                                                                             \
    _Pragma("unroll")                                                           \
    for (int mt = 0; mt < 2; ++mt)                                              \
      dst[mt] = *(const short8*)&src[(mt * 16 + cl) * XPITCH + (s_) * 32 + q * 8]; \
  }

  // ---- prefetch FF1-B for chunk 0 (hides h-write + barrier) ----
  short8 pb1[2][2];
  FF_LDB(w1pk, pb1[0], 0, 0)
  FF_LDB(w1pk, pb1[1], 0, 1)

  // ---- h (bf16) -> bufA rows 0..31 ----
  if (mg == 0) {
#pragma unroll
    for (int nt = 0; nt < 4; ++nt) {
      const int col = ng * 64 + nt * 16 + cl;
      const float gv = g1[col], bv = b1[col];
#pragma unroll
      for (int mt = 0; mt < 2; ++mt)
#pragma unroll
        for (int reg = 0; reg < 4; ++reg) {
          const int row = mt * 16 + q * 4 + reg;
          const float hv = (acc[mt][nt][reg] - muL[row]) * invL[row] * gv + bv;
          bufA[row * XPITCH + col] = f2bf(hv);
        }
    }
  }
  __syncthreads();

  // ============ FFN: 4 chunks of 256 H-cols; wave tile 32 x 32 ============
  // asb double-buffered by chunk parity (one barrier per chunk).  Weight
  // prefetch decoupled from barriers: FF2-B issued before gelu+barrier,
  // next chunk's FF1-B issued before the barrier too.
  f32x4 acc2[2][2];
#pragma unroll
  for (int nt = 0; nt < 2; ++nt) {
    const float bv = bf2[wv * 32 + nt * 16 + cl];
#pragma unroll
    for (int mt = 0; mt < 2; ++mt) acc2[mt][nt] = (f32x4){bv, bv, bv, bv};
  }

  for (int c = 0; c < 4; ++c) {
    u16* asb = asbuf + (c & 1) * (MT * XPITCH);
    // FF1: rows 0..31 (mt) x chunk-cols [wv*32,+32), K = 256
    f32x4 acc1[2][2];
#pragma unroll
    for (int nt = 0; nt < 2; ++nt) {
      const float bv = bf1[c * 256 + wv * 32 + nt * 16 + cl];
#pragma unroll
      for (int mt = 0; mt < 2; ++mt) acc1[mt][nt] = (f32x4){bv, bv, bv, bv};
    }
    {
      short8 a2[2][2], b2r[2][2];
      FF_LDA(bufA, a2[0], 0)
      b2r[0][0] = pb1[0][0]; b2r[0][1] = pb1[0][1];
      FF_LDA(bufA, a2[1], 1)
      b2r[1][0] = pb1[1][0]; b2r[1][1] = pb1[1][1];
#pragma unroll
      for (int s = 0; s < 6; ++s) {
        const int cur = s & 1;
        __builtin_amdgcn_s_setprio(1);
#pragma unroll
        for (int mt = 0; mt < 2; ++mt)
#pragma unroll
          for (int nt = 0; nt < 2; ++nt)
            acc1[mt][nt] = MFMA(a2[cur][mt], b2r[cur][nt], acc1[mt][nt]);
        __builtin_amdgcn_s_setprio(0);
        FF_LDA(bufA, a2[cur], s + 2) FF_LDB(w1pk, b2r[cur], c, s + 2)
      }
      __builtin_amdgcn_s_setprio(1);
#pragma unroll
      for (int s = 6; s < 8; ++s) {
        const int cur = s & 1;
#pragma unroll
        for (int mt = 0; mt < 2; ++mt)
#pragma unroll
          for (int nt = 0; nt < 2; ++nt)
            acc1[mt][nt] = MFMA(a2[cur][mt], b2r[cur][nt], acc1[mt][nt]);
      }
      __builtin_amdgcn_s_setprio(0);
    }
    // prefetch FF2-B for this chunk (independent of asb -> hides gelu +
    // barrier + L2 latency)
    short8 pb2[2][2];
    FF_LDB(w2pk, pb2[0], c, 0)
    FF_LDB(w2pk, pb2[1], c, 1)
    // fast gelu -> asb (A-layout, chunk-local cols wv*32+nt*16+cl)
#pragma unroll
    for (int mt = 0; mt < 2; ++mt)
#pragma unroll
      for (int nt = 0; nt < 2; ++nt)
#pragma unroll
        for (int reg = 0; reg < 4; ++reg) {
          const float g = fast_gelu(acc1[mt][nt][reg]);
          asb[(mt * 16 + q * 4 + reg) * XPITCH + wv * 32 + nt * 16 + cl] = f2bf(g);
        }
    // prefetch next chunk's FF1-B before the barrier
    if (c < 3) {
      FF_LDB(w1pk, pb1[0], c + 1, 0)
      FF_LDB(w1pk, pb1[1], c + 1, 1)
    }
    __syncthreads();
    // FF2: rows 0..31 x out-cols [wv*32,+32), K = chunk's 256
    {
      short8 a2[2][2], b2r[2][2];
      FF_LDA(asb, a2[0], 0)
      b2r[0][0] = pb2[0][0]; b2r[0][1] = pb2[0][1];
      FF_LDA(asb, a2[1], 1)
      b2r[1][0] = pb2[1][0]; b2r[1][1] = pb2[1][1];
#pragma unroll
      for (int s = 0; s < 6; ++s) {
        const int cur = s & 1;
        __builtin_amdgcn_s_setprio(1);
#pragma unroll
        for (int mt = 0; mt < 2; ++mt)
#pragma unroll
          for (int nt = 0; nt < 2; ++nt)
            acc2[mt][nt] = MFMA(a2[cur][mt], b2r[cur][nt], acc2[mt][nt]);
        __builtin_amdgcn_s_setprio(0);
        FF_LDA(asb, a2[cur], s + 2) FF_LDB(w2pk, b2r[cur], c, s + 2)
      }
      __builtin_amdgcn_s_setprio(1);
#pragma unroll
      for (int s = 6; s < 8; ++s) {
        const int cur = s & 1;
#pragma unroll
        for (int mt = 0; mt < 2; ++mt)
#pragma unroll
          for (int nt = 0; nt < 2; ++nt)
            acc2[mt][nt] = MFMA(a2[cur][mt], b2r[cur][nt], acc2[mt][nt]);
      }
      __builtin_amdgcn_s_setprio(0);
    }
    // no trailing barrier: next chunk writes the other asb buffer
  }
#undef FF_LDA
#undef FF_LDB

  // ---- residual (h from bufA) + LN2 ----
  {
    float ps[2][4], ps2[2][4];
#pragma unroll
    for (int mt = 0; mt < 2; ++mt)
#pragma unroll
      for (int reg = 0; reg < 4; ++reg) {
        const int row = mt * 16 + q * 4 + reg;
        float s = 0.f, s2 = 0.f;
#pragma unroll
        for (int nt = 0; nt < 2; ++nt) {
          const int col = wv * 32 + nt * 16 + cl;
          const float y = acc2[mt][nt][reg] + bf2f(bufA[row * XPITCH + col]);
          acc2[mt][nt][reg] = y;
          s += y; s2 += y * y;
        }
#pragma unroll
        for (int off = 1; off < 16; off <<= 1) { s += __shfl_xor(s, off, 64); s2 += __shfl_xor(s2, off, 64); }
        ps[mt][reg] = s; ps2[mt][reg] = s2;
      }
    if (cl == 0) {
#pragma unroll
      for (int mt = 0; mt < 2; ++mt)
#pragma unroll
        for (int reg = 0; reg < 4; ++reg) {
          const int row = mt * 16 + q * 4 + reg;
          redS[wv][row] = ps[mt][reg]; redS2[wv][row] = ps2[mt][reg];
        }
    }
  }
  __syncthreads();
  if (tid < MT) {
    float s = 0.f, s2 = 0.f;
#pragma unroll
    for (int k = 0; k < 8; ++k) { s += redS[k][tid]; s2 += redS2[k][tid]; }
    const float mu = s * (1.f / DD);
    const float var = s2 * (1.f / DD) - mu * mu;
    muL[tid] = mu; invL[tid] = rsqrtf(var + EPSLN);
  }
  __syncthreads();

#pragma unroll
  for (int nt = 0; nt < 2; ++nt) {
    const int col = wv * 32 + nt * 16 + cl;
    const float gv = g2[col], bv = b2[col];
#pragma unroll
    for (int mt = 0; mt < 2; ++mt)
#pragma unroll
      for (int reg = 0; reg < 4; ++reg) {
        const int row = mt * 16 + q * 4 + reg;
        out[(tok0 + row) * DD + col] = (acc2[mt][nt][reg] - muL[row]) * invL[row] * gv + bv;
      }
  }
#undef bufB
}

// ---------------- launch ----------------
extern "C" void kernel_launch(void* const* d_in, const int* in_sizes, int n_in,
                              void* d_out, int out_size, void* d_ws, size_t ws_size,
                              hipStream_t stream) {
  const float* x    = (const float*)d_in[0];
  const float* wmix = (const float*)d_in[1];   // [3840][256]
  const float* bmix = (const float*)d_in[2];
  const float* g1   = (const float*)d_in[3];
  const float* b1   = (const float*)d_in[4];
  const float* wff1 = (const float*)d_in[5];   // [256][1024]
  const float* bff1 = (const float*)d_in[6];
  const float* wff2 = (const float*)d_in[7];   // [1024][256]
  const float* bff2 = (const float*)d_in[8];
  const float* g2   = (const float*)d_in[9];
  const float* b2   = (const float*)d_in[10];
  float* out = (float*)d_out;

  u16* wpk  = (u16*)d_ws;                // 120*8192 = 983040 elems (1.97 MB)
  u16* w1pk = wpk + 983040;              // 32*8192 = 262144
  u16* w2pk = w1pk + 262144;             // 262144

  // 184 slabs x 1024 fragments-of-8 = 188416 threads = 736 x 256
  k_prep<<<736, 256, 0, stream>>>(wmix, wff1, wff2, wpk, w1pk, w2pk);

  k_fused<<<512, 512, 0, stream>>>(x, wpk, bmix, g1, b1,
                                   w1pk, bff1, w2pk, bff2, g2, b2, out);
}